// Round 10
// baseline (6185.128 us; speedup 1.0000x reference)
//
#include <hip/hip_runtime.h>

#define B_   128
#define T_   512
#define KV_  128
#define H1_  512
#define L_   256
#define NVOC 30
#define NPRED (B_*L_*NVOC)
#define NTHR 512

typedef __attribute__((ext_vector_type(8))) short short8v;
typedef __attribute__((ext_vector_type(4))) float float4v;

__device__ __forceinline__ float bf2f(unsigned short u) {
  union { unsigned int u; float f; } c; c.u = ((unsigned int)u) << 16; return c.f;
}
__device__ __forceinline__ unsigned short f2bf(float f) {
  union { float f; unsigned int u; } c; c.f = f;
  unsigned int r = (c.u + 0x7fffu + ((c.u >> 16) & 1u)) >> 16;
  return (unsigned short)r;
}
__device__ __forceinline__ float sigm(float x) { return 1.0f / (1.0f + __expf(-x)); }
__device__ __forceinline__ float tanhh(float x) { return 1.0f - 2.0f / (1.0f + __expf(2.0f * x)); }

// agent-scope point-coherent load/store (no cache-wide fences)
__device__ __forceinline__ unsigned int aloadu(const unsigned int* p) {
  return __hip_atomic_load((unsigned int*)p, __ATOMIC_RELAXED, __HIP_MEMORY_SCOPE_AGENT);
}
__device__ __forceinline__ void astoreu(unsigned int* p, unsigned int v) {
  __hip_atomic_store(p, v, __ATOMIC_RELAXED, __HIP_MEMORY_SCOPE_AGENT);
}
__device__ __forceinline__ unsigned long long aloadu64(const unsigned long long* p) {
  return __hip_atomic_load((unsigned long long*)p, __ATOMIC_RELAXED, __HIP_MEMORY_SCOPE_AGENT);
}
__device__ __forceinline__ void astoreu64(unsigned long long* p, unsigned long long v) {
  __hip_atomic_store(p, v, __ATOMIC_RELAXED, __HIP_MEMORY_SCOPE_AGENT);
}
__device__ __forceinline__ float4v mfma16(short8v a, short8v b, float4v c) {
  return __builtin_amdgcn_mfma_f32_16x16x32_bf16(a, b, c, 0, 0, 0);
}

struct DecParams {
  const int* y; const int* enc_len;
  const float* W_ih1; const float* W_hh1;
  const float* W_ih2; const float* W_hh2;
  const float* b_ih2; const float* b_hh2;
  const float* table; const unsigned int* keyRM; const float* value;
  unsigned int* H1hi; unsigned int* H1lo;       // [2][128][256] bf16x2 (dim pairs)
  unsigned long long* H2hi64;                   // [2][128][64] {pair | gen}
  unsigned long long* H2lo64;
  unsigned long long* CTXhi64;                  // [128][64] {pair | gen}
  unsigned long long* CTXlo64;
  float* qstore; float* ctxstore; float* attn_out;
  int* flags;                                   // [0..127] h1Flag(lb) only
};

// ---------------------------------------------------------------------------
// prep: emb-gate table, swizzled row-major bf16 key, zero state+gens+flags
// ---------------------------------------------------------------------------
__global__ void prep_kernel(const float* __restrict__ key,
                            const float* __restrict__ emb_W, const float* __restrict__ W_ih1,
                            const float* __restrict__ b_ih1, const float* __restrict__ b_hh1,
                            float* __restrict__ table, unsigned int* __restrict__ keyRM,
                            float* __restrict__ zbase) {
  const int NT_TAB = 31 * 2048;
  const int NT_KEY = B_ * T_ * 64;                       // 4194304 uints
  // zero: H1hi/H1lo (2*65536 f32) + H2 u64 (2*32768) + CTX u64 (2*16384) + flags
  const int NT_ZER = 2 * 65536 + 2 * 32768 + 2 * 16384 + 384;   // 229760
  const int total = NT_TAB + NT_KEY + NT_ZER;
  for (int i = blockIdx.x * blockDim.x + threadIdx.x; i < total;
       i += gridDim.x * blockDim.x) {
    if (i < NT_TAB) {
      int row = i & 2047, v = i >> 11;
      float acc = b_ih1[row] + b_hh1[row];
      if (v < NVOC) {
        const float* e = emb_W + v * 256;
        const float* w = W_ih1 + row * 384;
        #pragma unroll 4
        for (int k = 0; k < 256; ++k) acc += e[k] * w[k];
      }
      table[v * 2048 + row] = acc;
    } else if (i < NT_TAB + NT_KEY) {
      int j = i - NT_TAB;
      int dp = j & 63, r = j >> 6;        // r = b*512 + t
      int tt = r & 511, b = r >> 9;
      int src = (b * T_ + tt) * KV_ + 2 * dp;
      unsigned int lo = f2bf(key[src]), hi = f2bf(key[src + 1]);
      keyRM[(r << 6) + (dp ^ ((tt & 7) << 2))] = lo | (hi << 16);
    } else {
      zbase[i - NT_TAB - NT_KEY] = 0.0f;
    }
  }
}

// ---------------------------------------------------------------------------
// persistent kernel. Cross-block sync:
//  - ctx and h2 travel as GEN-TAGGED u64 atoms {bf16x2 | gen}: producer just
//    stores (self-validating, no flag, no drain); consumer sentinel-polls one
//    word then bulk-loads+verifies => detect+data in ~1 L3 round trip.
//    gen: ctx[t] -> t+1 (init 0 = ctx[-1]); h2[t] -> t+1 (double-buffered).
//    Lap-freedom by transitive ordering through the dependency cycle.
//  - h1 keeps flag protocol (bulk LDS-staged consumer G1h); G2h now reads h1
//    via register A-frags (all loads up front, one RT, waves 0-1 only).
// ---------------------------------------------------------------------------
__global__ void __launch_bounds__(NTHR) decoder_main(DecParams P) {
  __shared__ __align__(16) unsigned char smem[145664];
  const int blk = blockIdx.x, tid = threadIdx.x;
  const int lane = tid & 63, w = tid >> 6;
  const int lr = lane & 15, lk = lane >> 4;

  if (blk < B_) {
    // ======================= att role: MFMA attention =======================
    float* e_as = (float*)(smem + 131072);
    unsigned int* a_hl = (unsigned int*)(smem + 133120);
    float* red  = (float*)(smem + 135168);
    const int b = blk;

    { const uint4* src = (const uint4*)(P.keyRM + (size_t)b * (T_ * 64));
      uint4* dst = (uint4*)smem;
      for (int i = tid; i < (T_ * 64) / 4; i += NTHR) dst[i] = src[i]; }
    short8v vfragv[16];           // V[t=ks*32+lk*8+j][d=w*16+lr]
    { const float* vb = P.value + (size_t)b * T_ * KV_ + (w * 16 + lr);
      #pragma unroll
      for (int ks = 0; ks < 16; ++ks) {
        union { unsigned short us[8]; short8v s; } tv;
        #pragma unroll
        for (int j = 0; j < 8; ++j) tv.us[j] = f2bf(vb[(ks * 32 + lk * 8 + j) * KV_]);
        vfragv[ks] = tv.s;
      } }
    const int len = P.enc_len[b];
    const float SCALE = 0.08838834764831845f;          // 1/sqrt(128)
    __syncthreads();

    for (int t = 0; t < L_; ++t) {
      const int np = (t & 1) ^ 1;
      // ---- q: poll gen-tagged h2[t] (want gen t+1), build hi/lo B-frags ----
      union frag_t { unsigned int u[4]; short8v s; };
      frag_t qh[4], ql[4];
      {
        const unsigned long long* Qh = P.H2hi64 + np * (B_ * 64) + b * 64;
        const unsigned long long* Ql = P.H2lo64 + np * (B_ * 64) + b * 64;
        const unsigned int want = (unsigned int)(t + 1);
        while ((unsigned int)(aloadu64(Qh + lk * 4) >> 32) != want) {}
        unsigned long long vh[16], vl[16];
        bool okall;
        do {
          #pragma unroll
          for (int ks = 0; ks < 4; ++ks)
            #pragma unroll
            for (int j = 0; j < 4; ++j) {
              vh[ks * 4 + j] = aloadu64(Qh + ks * 16 + lk * 4 + j);
              vl[ks * 4 + j] = aloadu64(Ql + ks * 16 + lk * 4 + j);
            }
          bool ok = true;
          #pragma unroll
          for (int ii = 0; ii < 16; ++ii)
            ok = ok && ((unsigned int)(vh[ii] >> 32) == want)
                    && ((unsigned int)(vl[ii] >> 32) == want);
          okall = __all(ok);
        } while (!okall);
        #pragma unroll
        for (int ks = 0; ks < 4; ++ks)
          #pragma unroll
          for (int j = 0; j < 4; ++j) {
            qh[ks].u[j] = (unsigned int)vh[ks * 4 + j];
            ql[ks].u[j] = (unsigned int)vl[ks * 4 + j];
          }
      }
      // ---- energy: e[t] = K @ q via MFMA (A=K rows=t, B=q) ----
      #pragma unroll
      for (int i = 0; i < 4; ++i) {
        const int t0 = (w * 4 + i) * 16;
        const int tloc = t0 + lr;
        const unsigned char* rowp = smem + tloc * 256;
        const int sw = (tloc & 7) << 4;
        float4v acc = {0.0f, 0.0f, 0.0f, 0.0f};
        #pragma unroll
        for (int ks = 0; ks < 4; ++ks) {
          short8v av = *(const short8v*)(rowp + ((ks * 64 + lk * 16) ^ sw));
          acc = mfma16(av, qh[ks].s, acc);
          acc = mfma16(av, ql[ks].s, acc);
        }
        if (lr == 0) {
          #pragma unroll
          for (int j2 = 0; j2 < 4; ++j2) e_as[t0 + lk * 4 + j2] = acc[j2];
        }
      }
      __syncthreads();
      // ---- softmax over T ----
      float e = (tid < len) ? e_as[tid] * SCALE : -8.8388348e7f;  // (-1e9)*scale
      float m = e;
      #pragma unroll
      for (int off = 32; off > 0; off >>= 1) m = fmaxf(m, __shfl_xor(m, off));
      if (lane == 0) red[w] = m;
      __syncthreads();
      float M = red[0];
      #pragma unroll
      for (int i2 = 1; i2 < 8; ++i2) M = fmaxf(M, red[i2]);
      float pe = __expf(e - M);
      float s = pe;
      #pragma unroll
      for (int off = 32; off > 0; off >>= 1) s += __shfl_xor(s, off);
      if (lane == 0) red[8 + w] = s;
      {
        unsigned short hi = f2bf(pe);
        unsigned short lo = f2bf(pe - bf2f(hi));
        a_hl[tid] = (unsigned int)hi | ((unsigned int)lo << 16);
      }
      __syncthreads();
      float S = 0.0f;
      #pragma unroll
      for (int i2 = 0; i2 < 8; ++i2) S += red[8 + i2];
      const float invS = 1.0f / S;
      // ---- PV: ctx = a @ V via MFMA (A=a hi/lo, B=V regs) ----
      float4v acc0 = {0.0f, 0.0f, 0.0f, 0.0f};
      float4v acc1 = {0.0f, 0.0f, 0.0f, 0.0f};
      #pragma unroll
      for (int ks = 0; ks < 16; ++ks) {
        const unsigned int* ap = a_hl + ks * 32 + lk * 8;
        uint4 ua = *(const uint4*)(ap);
        uint4 ub = *(const uint4*)(ap + 4);
        union { unsigned short us[8]; short8v s; } ah, al;
        ah.us[0] = (unsigned short)ua.x;  al.us[0] = (unsigned short)(ua.x >> 16);
        ah.us[1] = (unsigned short)ua.y;  al.us[1] = (unsigned short)(ua.y >> 16);
        ah.us[2] = (unsigned short)ua.z;  al.us[2] = (unsigned short)(ua.z >> 16);
        ah.us[3] = (unsigned short)ua.w;  al.us[3] = (unsigned short)(ua.w >> 16);
        ah.us[4] = (unsigned short)ub.x;  al.us[4] = (unsigned short)(ub.x >> 16);
        ah.us[5] = (unsigned short)ub.y;  al.us[5] = (unsigned short)(ub.y >> 16);
        ah.us[6] = (unsigned short)ub.z;  al.us[6] = (unsigned short)(ub.z >> 16);
        ah.us[7] = (unsigned short)ub.w;  al.us[7] = (unsigned short)(ub.w >> 16);
        acc0 = mfma16(ah.s, vfragv[ks], acc0);
        acc1 = mfma16(al.s, vfragv[ks], acc1);
      }
      float cv = (acc0[0] + acc1[0]) * invS;           // D row0 at lanes 0..15
      float cvp = __shfl_xor(cv, 1);
      if (lane < 16) {
        const int d = w * 16 + lane;
        P.ctxstore[((size_t)t * B_ + b) * KV_ + d] = cv;
        if (!(lane & 1)) {
          unsigned short h0 = f2bf(cv),  l0 = f2bf(cv - bf2f(h0));
          unsigned short h1v = f2bf(cvp), l1 = f2bf(cvp - bf2f(h1v));
          unsigned long long g = ((unsigned long long)(t + 1)) << 32;
          astoreu64(&P.CTXhi64[b * 64 + (d >> 1)],
                    g | (unsigned long long)((unsigned int)h0 | ((unsigned int)h1v << 16)));
          astoreu64(&P.CTXlo64[b * 64 + (d >> 1)],
                    g | (unsigned long long)((unsigned int)l0 | ((unsigned int)l1 << 16)));
        }
      }
      if (b == 0) P.attn_out[t * T_ + tid] = pe * invS;
      // no trailing barrier: gen-tagged stores are self-validating
    }
  } else {
    // ================= lstm role: LSTM1 + LSTM2 slices (MFMA) =================
    unsigned short* W1l = (unsigned short*)smem;             // [64][648] bf16
    unsigned short* W2l = (unsigned short*)(smem + 82944);   // [16][648] bf16
    unsigned short* xT  = (unsigned short*)(smem + 103680);  // [32][520] bf16
    unsigned int*   xTu = (unsigned int*)(smem + 103680);    // [32][260]
    float* gbuf = (float*)(smem + 136960);                   // [32][68] f32
    const int lb = blk - B_;
    const int ds = lb & 31, g32 = (lb >> 5) << 5;

    for (int idx = tid; idx < 64 * 640; idx += NTHR) {       // W1 slice
      int r = idx / 640, k = idx - r * 640;
      int grow = (r & 3) * 512 + ds * 16 + (r >> 2);
      float wv = (k < 128) ? P.W_ih1[grow * 384 + 256 + k]
                           : P.W_hh1[grow * 512 + (k - 128)];
      W1l[r * 648 + k] = f2bf(wv);
    }
    for (int idx = tid; idx < 16 * 640; idx += NTHR) {       // W2 slice
      int r = idx / 640, k = idx - r * 640;
      int grow = (r & 3) * 128 + ds * 4 + (r >> 2);
      float wv = (k < 512) ? P.W_ih2[grow * 512 + k]
                           : P.W_hh2[grow * 128 + (k - 512)];
      W2l[r * 648 + k] = f2bf(wv);
    }
    float c1 = 0.0f;                   // cell1: thread (b=tid>>4, d=tid&15)
    float c2 = 0.0f;                   // cell2: thread (b=tid>>2, d=tid&3), tid<128
    float bi2[4];
    {
      const int dloc = tid & 3;
      #pragma unroll
      for (int gq = 0; gq < 4; ++gq) {
        const int grow = gq * 128 + ds * 4 + dloc;
        bi2[gq] = P.b_ih2[grow] + P.b_hh2[grow];
      }
    }
    __syncthreads();

    const int mt = w & 1, nt = w >> 1;

    for (int t = 0; t < L_; ++t) {
      const int p = t & 1, np = p ^ 1;
      // ---- waitA: mates h1Flag >= t (for G1h staging of h1[t-1]) ----
      if (tid < 64) {
        const int idx = g32 + (tid & 31);
        while (true) {
          int v = __hip_atomic_load(&P.flags[idx], __ATOMIC_RELAXED, __HIP_MEMORY_SCOPE_AGENT);
          if (__all(v >= t)) break;
          __builtin_amdgcn_s_sleep(1);
        }
      }
      __syncthreads();

      // ---- prefetch h1[t-1] hi+lo into regs (one L3 RT) ----
      unsigned int rh[16], rl[16];
      {
        const unsigned int* Sh = P.H1hi + p * (B_ * 256);
        const unsigned int* Sl = P.H1lo + p * (B_ * 256);
        #pragma unroll
        for (int ii = 0; ii < 16; ++ii) {
          int i = tid + ii * NTHR; int bq = i >> 8, kp = i & 255;
          int off = (g32 + bq) * 256 + kp;
          rh[ii] = aloadu(Sh + off);
          rl[ii] = aloadu(Sl + off);
        }
      }

      // ======== G2s: acc2 = W2[:,512:640] @ h2[t-1] (gen-tagged, want t) ====
      float4v acc2 = {0.0f, 0.0f, 0.0f, 0.0f};
      if (w < 2) {
        const int arow = (g32 + w * 16 + lr) * 64 + lk * 4;
        const unsigned long long* Sh = P.H2hi64 + p * (B_ * 64) + arow;
        const unsigned long long* Sl = P.H2lo64 + p * (B_ * 64) + arow;
        const unsigned int want = (unsigned int)t;
        while ((unsigned int)(aloadu64(Sh) >> 32) != want) {}
        unsigned long long vh[16], vl[16];
        bool okall;
        do {
          #pragma unroll
          for (int ks = 0; ks < 4; ++ks)
            #pragma unroll
            for (int j = 0; j < 4; ++j) {
              vh[ks * 4 + j] = aloadu64(Sh + ks * 16 + j);
              vl[ks * 4 + j] = aloadu64(Sl + ks * 16 + j);
            }
          bool ok = true;
          #pragma unroll
          for (int ii = 0; ii < 16; ++ii)
            ok = ok && ((unsigned int)(vh[ii] >> 32) == want)
                    && ((unsigned int)(vl[ii] >> 32) == want);
          okall = __all(ok);
        } while (!okall);
        #pragma unroll
        for (int ks = 0; ks < 4; ++ks) {
          union { unsigned int u[4]; short8v s; } ah, al;
          #pragma unroll
          for (int j = 0; j < 4; ++j) { ah.u[j] = (unsigned int)vh[ks * 4 + j];
                                        al.u[j] = (unsigned int)vl[ks * 4 + j]; }
          short8v bv = *(const short8v*)(W2l + lr * 648 + 512 + lk * 8 + ks * 32);
          acc2 = mfma16(ah.s, bv, acc2);
          acc2 = mfma16(al.s, bv, acc2);
        }
      }

      // ======== G1h: acc1 = W1[:,128:640] @ h1[t-1] (pipelined hi/lo) =====
      float4v acc1 = {0.0f, 0.0f, 0.0f, 0.0f};
      #pragma unroll
      for (int ii = 0; ii < 16; ++ii) {
        int i = tid + ii * NTHR; xTu[(i >> 8) * 260 + (i & 255)] = rh[ii];
      }
      __syncthreads();
      {
        const unsigned short* ap = xT + (mt * 16 + lr) * 520 + lk * 8;
        const unsigned short* bp = W1l + (nt * 16 + lr) * 648 + 128 + lk * 8;
        #pragma unroll
        for (int ks = 0; ks < 16; ++ks)
          acc1 = mfma16(*(const short8v*)(ap + ks * 32),
                        *(const short8v*)(bp + ks * 32), acc1);
      }
      __syncthreads();
      #pragma unroll
      for (int ii = 0; ii < 16; ++ii) {
        int i = tid + ii * NTHR; xTu[(i >> 8) * 260 + (i & 255)] = rl[ii];
      }
      __syncthreads();
      {
        const unsigned short* ap = xT + (mt * 16 + lr) * 520 + lk * 8;
        const unsigned short* bp = W1l + (nt * 16 + lr) * 648 + 128 + lk * 8;
        #pragma unroll
        for (int ks = 0; ks < 16; ++ks)
          acc1 = mfma16(*(const short8v*)(ap + ks * 32),
                        *(const short8v*)(bp + ks * 32), acc1);
      }

      // ======== G1c: acc1 += W1[:,0:128] @ ctx[t-1] (gen-tagged, want t) ====
      {
        const int arow = (g32 + mt * 16 + lr) * 64 + lk * 4;
        const unsigned long long* Ch = P.CTXhi64 + arow;
        const unsigned long long* Cl = P.CTXlo64 + arow;
        const unsigned int want = (unsigned int)t;
        while ((unsigned int)(aloadu64(Ch) >> 32) != want) {}
        unsigned long long vh[16], vl[16];
        bool okall;
        do {
          #pragma unroll
          for (int ks = 0; ks < 4; ++ks)
            #pragma unroll
            for (int j = 0; j < 4; ++j) {
              vh[ks * 4 + j] = aloadu64(Ch + ks * 16 + j);
              vl[ks * 4 + j] = aloadu64(Cl + ks * 16 + j);
            }
          bool ok = true;
          #pragma unroll
          for (int ii = 0; ii < 16; ++ii)
            ok = ok && ((unsigned int)(vh[ii] >> 32) == want)
                    && ((unsigned int)(vl[ii] >> 32) == want);
          okall = __all(ok);
        } while (!okall);
        #pragma unroll
        for (int ks = 0; ks < 4; ++ks) {
          union { unsigned int u[4]; short8v s; } ah, al;
          #pragma unroll
          for (int j = 0; j < 4; ++j) { ah.u[j] = (unsigned int)vh[ks * 4 + j];
                                        al.u[j] = (unsigned int)vl[ks * 4 + j]; }
          short8v bv = *(const short8v*)(W1l + (nt * 16 + lr) * 648 + lk * 8 + ks * 32);
          acc1 = mfma16(ah.s, bv, acc1);
          acc1 = mfma16(al.s, bv, acc1);
        }
      }
      {
        const int m0 = mt * 16 + lk * 4, n = nt * 16 + lr;
        #pragma unroll
        for (int j = 0; j < 4; ++j) gbuf[(m0 + j) * 68 + n] = acc1[j];
      }
      __syncthreads();
      // ---- cell1 -> publish h1[t] (u32 arrays + flag protocol) ----
      {
        const int bq = tid >> 4, d = tid & 15, gb = g32 + bq;
        float4 gv = *(const float4*)&gbuf[bq * 68 + 4 * d];
        const int ci = (t == 0) ? NVOC : P.y[gb * L_ + (t - 1)];
        const int dg = ds * 16 + d;
        const float* tb = P.table + ci * 2048 + dg;
        float gi = gv.x + tb[0];
        float gf = gv.y + tb[512];
        float gg = gv.z + tb[1024];
        float go = gv.w + tb[1536];
        float cn = sigm(gf) * c1 + sigm(gi) * tanhh(gg);
        float hn = sigm(go) * tanhh(cn);
        c1 = cn;
        float hnp = __shfl_xor(hn, 1);
        if (!(d & 1)) {
          unsigned short h0 = f2bf(hn),  l0 = f2bf(hn - bf2f(h0));
          unsigned short h1v = f2bf(hnp), l1 = f2bf(hnp - bf2f(h1v));
          astoreu(&P.H1hi[np * (B_ * 256) + gb * 256 + ds * 8 + (d >> 1)],
                  (unsigned int)h0 | ((unsigned int)h1v << 16));
          astoreu(&P.H1lo[np * (B_ * 256) + gb * 256 + ds * 8 + (d >> 1)],
                  (unsigned int)l0 | ((unsigned int)l1 << 16));
        }
      }
      __syncthreads();                                 // drain h1 stores
      if (tid == 0)
        __hip_atomic_store(&P.flags[lb], t + 1, __ATOMIC_RELAXED, __HIP_MEMORY_SCOPE_AGENT);
      // ---- waitD: mates h1Flag >= t+1 ----
      if (tid < 64) {
        const int idx = g32 + (tid & 31);
        while (true) {
          int v = __hip_atomic_load(&P.flags[idx], __ATOMIC_RELAXED, __HIP_MEMORY_SCOPE_AGENT);
          if (__all(v >= t + 1)) break;
          __builtin_amdgcn_s_sleep(1);
        }
      }
      __syncthreads();
      // ======== G2h: acc2 += W2[:,0:512] @ h1[t] (register A-frags) ========
      if (w < 2) {
        const unsigned int* Sh = P.H1hi + np * (B_ * 256) + (g32 + w * 16 + lr) * 256 + lk * 4;
        const unsigned int* Sl = P.H1lo + np * (B_ * 256) + (g32 + w * 16 + lr) * 256 + lk * 4;
        unsigned int gh[64], gl[64];
        #pragma unroll
        for (int ks = 0; ks < 16; ++ks)
          #pragma unroll
          for (int j = 0; j < 4; ++j) {
            gh[ks * 4 + j] = aloadu(Sh + ks * 16 + j);
            gl[ks * 4 + j] = aloadu(Sl + ks * 16 + j);
          }
        #pragma unroll
        for (int ks = 0; ks < 16; ++ks) {
          union { unsigned int u[4]; short8v s; } ah, al;
          #pragma unroll
          for (int j = 0; j < 4; ++j) { ah.u[j] = gh[ks * 4 + j];
                                        al.u[j] = gl[ks * 4 + j]; }
          short8v bv = *(const short8v*)(W2l + lr * 648 + lk * 8 + ks * 32);
          acc2 = mfma16(ah.s, bv, acc2);
          acc2 = mfma16(al.s, bv, acc2);
        }
        const int m0 = w * 16 + lk * 4, n = lr;
        #pragma unroll
        for (int j = 0; j < 4; ++j) gbuf[(m0 + j) * 68 + n] = acc2[j];
      }
      __syncthreads();
      // ---- cell2 -> publish h2[t] as gen-tagged u64; qstore f32 ----
      if (tid < 128) {
        const int bq = tid >> 2, dloc = tid & 3, gb = g32 + bq;
        float4 gv = *(const float4*)&gbuf[bq * 68 + 4 * dloc];
        float gi = gv.x + bi2[0];
        float gf = gv.y + bi2[1];
        float gg = gv.z + bi2[2];
        float go = gv.w + bi2[3];
        float cn = sigm(gf) * c2 + sigm(gi) * tanhh(gg);
        float hn = sigm(go) * tanhh(cn);
        c2 = cn;
        P.qstore[((size_t)t * B_ + gb) * KV_ + ds * 4 + dloc] = hn;
        float hnp = __shfl_xor(hn, 1);
        if (!(dloc & 1)) {
          unsigned short h0 = f2bf(hn),  l0 = f2bf(hn - bf2f(h0));
          unsigned short h1v = f2bf(hnp), l1 = f2bf(hnp - bf2f(h1v));
          unsigned long long g = ((unsigned long long)(t + 1)) << 32;
          astoreu64(&P.H2hi64[np * (B_ * 64) + gb * 64 + ds * 2 + (dloc >> 1)],
                    g | (unsigned long long)((unsigned int)h0 | ((unsigned int)h1v << 16)));
          astoreu64(&P.H2lo64[np * (B_ * 64) + gb * 64 + ds * 2 + (dloc >> 1)],
                    g | (unsigned long long)((unsigned int)l0 | ((unsigned int)l1 << 16)));
        }
      }
      // no trailing barrier: gen-tagged stores are self-validating
    }
  }
}

// ---------------------------------------------------------------------------
// tail: predictions[b][t][v] = [q,ctx] @ emb_W.T + out_b   (fully parallel)
// ---------------------------------------------------------------------------
__global__ void pred_tail(const float* __restrict__ qstore, const float* __restrict__ ctxstore,
                          const float* __restrict__ emb_W, const float* __restrict__ out_b,
                          float* __restrict__ preds) {
  int o = blockIdx.x * 256 + threadIdx.x;
  if (o >= NPRED) return;
  int v = o % NVOC;
  int bt = o / NVOC;
  int b = bt >> 8, t = bt & 255;
  const float* q  = qstore   + ((size_t)t * B_ + b) * KV_;
  const float* cx = ctxstore + ((size_t)t * B_ + b) * KV_;
  const float* er = emb_W + v * 256;
  float acc = out_b[v];
  #pragma unroll 4
  for (int e = 0; e < 128; ++e) acc += q[e] * er[e] + cx[e] * er[128 + e];
  preds[o] = acc;
}

extern "C" void kernel_launch(void* const* d_in, const int* in_sizes, int n_in,
                              void* d_out, int out_size, void* d_ws, size_t ws_size,
                              hipStream_t stream) {
  const float* key    = (const float*)d_in[0];
  const float* value  = (const float*)d_in[1];
  const int*   enclen = (const int*)d_in[2];
  const int*   y      = (const int*)d_in[3];
  const float* emb_W  = (const float*)d_in[4];
  const float* W_ih1  = (const float*)d_in[5];
  const float* W_hh1  = (const float*)d_in[6];
  const float* b_ih1  = (const float*)d_in[7];
  const float* b_hh1  = (const float*)d_in[8];
  const float* W_ih2  = (const float*)d_in[9];
  const float* W_hh2  = (const float*)d_in[10];
  const float* b_ih2  = (const float*)d_in[11];
  const float* b_hh2  = (const float*)d_in[12];
  const float* out_b  = (const float*)d_in[13];

  float* f = (float*)d_ws;
  float* table = f;                            f += 31 * 2048;
  unsigned int* keyRM = (unsigned int*)f;      f += B_ * T_ * 64;
  unsigned int* H1hi = (unsigned int*)f;       f += 2 * B_ * 256;   // zero-region start
  unsigned int* H1lo = (unsigned int*)f;       f += 2 * B_ * 256;
  unsigned long long* H2hi64 = (unsigned long long*)f;  f += 2 * (2 * B_ * 64);
  unsigned long long* H2lo64 = (unsigned long long*)f;  f += 2 * (2 * B_ * 64);
  unsigned long long* CTXhi64 = (unsigned long long*)f; f += 2 * (B_ * 64);
  unsigned long long* CTXlo64 = (unsigned long long*)f; f += 2 * (B_ * 64);
  int*   flags = (int*)f;                      f += 384;
  float* qstore   = f;                         f += (size_t)L_ * B_ * KV_;
  float* ctxstore = f;                         f += (size_t)L_ * B_ * KV_;

  float* preds    = (float*)d_out;
  float* attn_out = preds + NPRED;

  prep_kernel<<<4096, 256, 0, stream>>>(key, emb_W, W_ih1, b_ih1, b_hh1,
                                        table, keyRM, (float*)H1hi);

  DecParams P{ y, enclen, W_ih1, W_hh1, W_ih2, W_hh2, b_ih2, b_hh2,
               table, keyRM, value, H1hi, H1lo, H2hi64, H2lo64, CTXhi64, CTXlo64,
               qstore, ctxstore, attn_out, flags };
  void* kargs[] = { (void*)&P };
  hipLaunchCooperativeKernel((void*)decoder_main, dim3(256), dim3(NTHR), kargs, 0, stream);

  pred_tail<<<(NPRED + 255) / 256, 256, 0, stream>>>(qstore, ctxstore, emb_W, out_b, preds);
}